// Round 3
// baseline (591.693 us; speedup 1.0000x reference)
//
#include <hip/hip_runtime.h>
#include <math.h>

// Round 8: GEMM rebuilt — 256x128 block tile, 4 waves with 128x64 wave tiles
// (375 B LDS-read per MFMA vs 512 at 64x64), XOR bank-swizzle applied as
// pre-swizzled GLOBAL source + swizzled ds_read (LDS dest stays linear for
// global_load_lds), 3 LDS buffers with distance-2 DMA prefetch and counted
// vmcnt(6) (never drains in steady state), one barrier per K-iter, setprio
// around MFMA clusters. Flash (paired q-tiles) / LN / wconv unchanged.
//
// ws: [0,16M) lnbuf | [16,48M) qk | [48,64M) vT | [64,80M) ybuf
//     [80,144M) h | [144,170M) wT

#define M_ROWS 8192
#define T_SEQ 2048
#define N_EMB 1024
#define N_HEADS 16
#define HEAD_D 64

typedef _Float16 f16;
typedef __attribute__((ext_vector_type(8))) _Float16 f16x8;
typedef __attribute__((ext_vector_type(4))) _Float16 f16x4;
typedef __attribute__((ext_vector_type(4))) float f32x4;

__device__ __forceinline__ void async16(void* lds, const void* g) {
    __builtin_amdgcn_global_load_lds(
        (const __attribute__((address_space(1))) unsigned int*)g,
        (__attribute__((address_space(3))) unsigned int*)lds, 16, 0, 0);
}

__device__ __forceinline__ float gelu_tanh(float v) {
    float u = 0.7978845608028654f * (v + 0.044715f * v * v * v);
    float e = __expf(2.0f * u);
    float t = 1.0f - 2.0f / (e + 1.0f);
    return 0.5f * v * (1.0f + t);
}

// ---------------------------------------------------------------- weight convert
__launch_bounds__(256)
__global__ void wconv_kernel(const float* __restrict__ W, f16* __restrict__ WT,
                             int K, int N) {
    __shared__ float t[32][33];
    int tx = threadIdx.x & 31, ty = threadIdx.x >> 5;
    int n0 = blockIdx.x * 32, k0 = blockIdx.y * 32;
    #pragma unroll
    for (int r = 0; r < 4; r++)
        t[ty * 4 + r][tx] = W[(size_t)(k0 + ty * 4 + r) * N + n0 + tx];
    __syncthreads();
    #pragma unroll
    for (int r = 0; r < 4; r++)
        WT[(size_t)(n0 + ty * 4 + r) * K + k0 + tx] = (f16)t[tx][ty * 4 + r];
}

// ---------------------------------------------------------------- LayerNorm -> f16
__launch_bounds__(256)
__global__ void ln_kernel(const float* __restrict__ x, const float* __restrict__ g,
                          const float* __restrict__ b, f16* __restrict__ y) {
    int row = blockIdx.x;
    int tid = threadIdx.x;
    const float* xr = x + (size_t)row * N_EMB;
    float4 v = *(const float4*)(xr + tid * 4);
    float s  = v.x + v.y + v.z + v.w;
    float sq = v.x * v.x + v.y * v.y + v.z * v.z + v.w * v.w;
    #pragma unroll
    for (int off = 32; off > 0; off >>= 1) {
        s  += __shfl_down(s, off);
        sq += __shfl_down(sq, off);
    }
    __shared__ float ws_[4], wq_[4];
    __shared__ float mean_s, rstd_s;
    int lane = tid & 63, wid = tid >> 6;
    if (lane == 0) { ws_[wid] = s; wq_[wid] = sq; }
    __syncthreads();
    if (tid == 0) {
        float st = ws_[0] + ws_[1] + ws_[2] + ws_[3];
        float qt = wq_[0] + wq_[1] + wq_[2] + wq_[3];
        float mu = st * (1.0f / N_EMB);
        float var = qt * (1.0f / N_EMB) - mu * mu;
        mean_s = mu;
        rstd_s = rsqrtf(var + 1e-5f);
    }
    __syncthreads();
    float mu = mean_s, r = rstd_s;
    float4 gv = *(const float4*)(g + tid * 4);
    float4 bv = *(const float4*)(b + tid * 4);
    f16x4 o;
    o.x = (f16)((v.x - mu) * r * gv.x + bv.x);
    o.y = (f16)((v.y - mu) * r * gv.y + bv.y);
    o.z = (f16)((v.z - mu) * r * gv.z + bv.z);
    o.w = (f16)((v.w - mu) * r * gv.w + bv.w);
    *(f16x4*)(y + (size_t)row * N_EMB + tid * 4) = o;
}

// ---------------------------------------------------------------- GEMM f16 MFMA
// Block tile 256x128, BK=32, 4 waves (2x2), wave tile 128x64 -> acc[8][4].
// LDS XOR-swizzle: logical granule q of row r lives at granule q^(r&3).
// Staged via pre-swizzled global source (LDS dest linear — gload_lds rule).
// 3 buffers, distance-2 prefetch, vmcnt(6) steady state, 1 barrier/iter.
// EPI: 0 f32 | 1 f32 + f32 residual | 2 gelu->f16 | 3 qkv split
template <int EPI>
__launch_bounds__(256, 2)
__global__ void gemm_f16(const f16* __restrict__ A, const f16* __restrict__ Bt,
                         const float* __restrict__ bias, const float* __restrict__ res,
                         float* __restrict__ Cf, f16* __restrict__ Ch,
                         f16* __restrict__ vT, int K, int N) {
    __shared__ f16 As[3][256 * 32];   // 48 KB
    __shared__ f16 Bs[3][128 * 32];   // 24 KB
    int tid = threadIdx.x;
    int lane = tid & 63, wave = tid >> 6;
    int wr = wave >> 1, wc = wave & 1;
    int quad = lane >> 4, l16 = lane & 15;

    // bijective XCD swizzle (all gemm grids divisible by 8)
    int nx = gridDim.x;
    int nwg = nx * gridDim.y;
    int orig = blockIdx.y * nx + blockIdx.x;
    int cpx = nwg >> 3;
    int swz = (orig & 7) * cpx + (orig >> 3);
    int m0 = (swz / nx) * 256, n0 = (swz % nx) * 128;

    // staging: one round = 256 thr x 16B = 4KB = 64 rows (row stride 64B).
    // thread covers (row = srow + 64*r, granule tid&3); source granule
    // pre-swizzled by ^(row&3) so swizzled READS return logical data.
    int srow = tid >> 2;
    int sg = (tid & 3) ^ (srow & 3);
    const f16* pA = A  + (size_t)(m0 + srow) * K + sg * 8;
    const f16* pB = Bt + (size_t)(n0 + srow) * K + sg * 8;
    char* dA = (char*)As + (size_t)tid * 16;
    char* dB = (char*)Bs + (size_t)tid * 16;

    int nt = K >> 5;

    // prologue: tiles 0 -> buf0, 1 -> buf1 (12 loads in flight)
    #pragma unroll
    for (int r = 0; r < 4; r++) async16(dA + r * 4096, pA + (size_t)(r * 64) * K);
    #pragma unroll
    for (int r = 0; r < 2; r++) async16(dB + r * 4096, pB + (size_t)(r * 64) * K);
    #pragma unroll
    for (int r = 0; r < 4; r++) async16(dA + 16384 + r * 4096, pA + (size_t)(r * 64) * K + 32);
    #pragma unroll
    for (int r = 0; r < 2; r++) async16(dB + 8192  + r * 4096, pB + (size_t)(r * 64) * K + 32);

    f32x4 acc[8][4] = {};
    int cswz = (quad ^ (l16 & 3)) * 8;
    int bufr = 0;
    for (int t = 0; t < nt; t++) {
        if (t + 1 < nt) asm volatile("s_waitcnt vmcnt(6)" ::: "memory");
        else            asm volatile("s_waitcnt vmcnt(0)" ::: "memory");
        __builtin_amdgcn_s_barrier();   // tile t visible; buf (t+2)%3 reads retired

        const f16* as = As[bufr];
        const f16* bs = Bs[bufr];
        int bn = bufr + 2 >= 3 ? bufr - 1 : bufr + 2;   // (t+2)%3
        bool pf = (t + 2 < nt);
        size_t koff = (size_t)(t + 2) * 32;

        f16x8 bf[4];
        #pragma unroll
        for (int j = 0; j < 4; j++)
            bf[j] = *(const f16x8*)&bs[(wc * 64 + j * 16 + l16) * 32 + cswz];

        // phase 1: stage 3 rounds of tile t+2, read m-half 0, 16 MFMA
        if (pf) {
            async16(dA + bn * 16384,        pA + koff);
            async16(dA + bn * 16384 + 4096, pA + (size_t)64 * K + koff);
            async16(dA + bn * 16384 + 8192, pA + (size_t)128 * K + koff);
        }
        f16x8 af[4];
        #pragma unroll
        for (int i = 0; i < 4; i++)
            af[i] = *(const f16x8*)&as[(wr * 128 + i * 16 + l16) * 32 + cswz];
        __builtin_amdgcn_s_setprio(1);
        #pragma unroll
        for (int i = 0; i < 4; i++)
            #pragma unroll
            for (int j = 0; j < 4; j++)
                acc[i][j] = __builtin_amdgcn_mfma_f32_16x16x32_f16(
                    af[i], bf[j], acc[i][j], 0, 0, 0);
        __builtin_amdgcn_s_setprio(0);

        // phase 2: stage remaining 3 rounds, read m-half 1, 16 MFMA
        if (pf) {
            async16(dA + bn * 16384 + 12288, pA + (size_t)192 * K + koff);
            async16(dB + bn * 8192,          pB + koff);
            async16(dB + bn * 8192 + 4096,   pB + (size_t)64 * K + koff);
        }
        #pragma unroll
        for (int i = 0; i < 4; i++)
            af[i] = *(const f16x8*)&as[(wr * 128 + (4 + i) * 16 + l16) * 32 + cswz];
        __builtin_amdgcn_s_setprio(1);
        #pragma unroll
        for (int i = 0; i < 4; i++)
            #pragma unroll
            for (int j = 0; j < 4; j++)
                acc[4 + i][j] = __builtin_amdgcn_mfma_f32_16x16x32_f16(
                    af[i], bf[j], acc[4 + i][j], 0, 0, 0);
        __builtin_amdgcn_s_setprio(0);

        bufr = bufr + 1 >= 3 ? 0 : bufr + 1;
    }

    // epilogue: C/D layout col=lane&15, row=quad*4+r
    #pragma unroll
    for (int i = 0; i < 8; i++) {
        int row0 = m0 + wr * 128 + i * 16 + quad * 4;
        #pragma unroll
        for (int j = 0; j < 4; j++) {
            int col = n0 + wc * 64 + j * 16 + l16;
            float bb = bias[col];
            if (EPI == 3) {
                if (n0 < 2048) {
                    #pragma unroll
                    for (int r = 0; r < 4; r++)
                        Ch[(size_t)(row0 + r) * 2048 + col] = (f16)(acc[i][j][r] + bb);
                } else {
                    int hh = (col - 2048) >> 6, dd = col & 63;
                    int bb_ = row0 >> 11, t0 = row0 & 2047;
                    f16x4 pk;
                    pk.x = (f16)(acc[i][j][0] + bb);
                    pk.y = (f16)(acc[i][j][1] + bb);
                    pk.z = (f16)(acc[i][j][2] + bb);
                    pk.w = (f16)(acc[i][j][3] + bb);
                    *(f16x4*)(vT + ((size_t)(bb_ * 16 + hh) * 64 + dd) * 2048 + t0) = pk;
                }
            } else {
                #pragma unroll
                for (int r = 0; r < 4; r++) {
                    size_t idx = (size_t)(row0 + r) * N + col;
                    float v = acc[i][j][r] + bb;
                    if (EPI == 1) v += res[idx];
                    if (EPI == 2) Ch[idx] = (f16)gelu_tanh(v);
                    else          Cf[idx] = v;
                }
            }
        }
    }
}

// ---------------------------------------------------------------- MFMA flash
// 256 thr = 4 waves; 128 q-rows per tile (wave w owns 32), 128-wide j-tiles.
// S^T = K.Q^T (C-layout: 4 consecutive j per lane). Q pre-scaled by 1/8.
// CAUSAL BALANCING: each block processes TWO q-tiles, qt = 15-x then qt = x,
// so every block does exactly 17 j-tile iterations. Grid = (8, 64) = 512
// blocks = 2 blocks/CU (LDS limit) -> all blocks co-resident, uniform work.
__launch_bounds__(256, 2)
__global__ void flash_kernel(const f16* __restrict__ qk, const f16* __restrict__ vT,
                             f16* __restrict__ y) {
    __shared__ __align__(16) char smem[67584];
    f16* Ks = (f16*)smem;                      // [128 j][8 g of 8 d], g^=(j&7)
    f16* Vs = (f16*)(smem + 16384);            // [64 d][16 g of 8 j], g^=(d&7)
    int tid = threadIdx.x;
    int lane = tid & 63, w = tid >> 6;
    int quad = lane >> 4, l16 = lane & 15;
    f16* Ps = (f16*)(smem + 32768 + w * 8704); // per-wave [32 q][136 j]

    int bh = blockIdx.y;
    int b = bh >> 4, h = bh & 15;

    for (int half = 0; half < 2; half++) {
        int qt = half ? (int)blockIdx.x : 15 - (int)blockIdx.x;
        int q0 = qt * 128;

        // Q B-frags, pre-scaled by 1/sqrt(D)=0.125 (exact in f16)
        f16x8 qf[2][2];
        #pragma unroll
        for (int qn = 0; qn < 2; qn++) {
            int q = q0 + w * 32 + qn * 16 + l16;
            #pragma unroll
            for (int dblk = 0; dblk < 2; dblk++) {
                f16x8 t = *(const f16x8*)(qk + (size_t)(b * T_SEQ + q) * 2048 +
                                          h * 64 + dblk * 32 + quad * 8);
                #pragma unroll
                for (int e = 0; e < 8; e++) t[e] = t[e] * (f16)0.125f;
                qf[qn][dblk] = t;
            }
        }

        float m_r[2] = {-INFINITY, -INFINITY};
        float l_r[2] = {0.0f, 0.0f};
        f32x4 Oacc[2][4] = {};

        for (int jt = 0; jt <= qt; jt++) {
            int j0 = jt * 128;
            __syncthreads();   // prior iter's (or prior half's) LDS reads done
            #pragma unroll
            for (int i = 0; i < 4; i++) {
                int L = i * 256 + tid;
                int j = L >> 3, g1 = L & 7;
                int g = g1 ^ (j & 7);
                async16((char*)Ks + (size_t)L * 16,
                        qk + (size_t)(b * T_SEQ + j0 + j) * 2048 + 1024 + h * 64 + g * 8);
            }
            #pragma unroll
            for (int i = 0; i < 4; i++) {
                int L = i * 256 + tid;
                int d = L >> 4, g1 = L & 15;
                int g = (g1 & 8) | ((g1 ^ d) & 7);
                async16((char*)Vs + (size_t)L * 16,
                        vT + ((size_t)(bh) * 64 + d) * 2048 + j0 + g * 8);
            }
            __syncthreads();

            // S^T = K . Q^T (pre-scaled)
            f32x4 S[8][2];
            #pragma unroll
            for (int jm = 0; jm < 8; jm++) {
                f16x8 kf[2];
                #pragma unroll
                for (int dblk = 0; dblk < 2; dblk++) {
                    int j = jm * 16 + l16;
                    int g = (dblk * 4 + quad) ^ (j & 7);
                    kf[dblk] = *(const f16x8*)(Ks + (size_t)(j * 8 + g) * 8);
                }
                #pragma unroll
                for (int qn = 0; qn < 2; qn++) {
                    f32x4 s = {};
                    s = __builtin_amdgcn_mfma_f32_16x16x32_f16(kf[0], qf[qn][0], s, 0, 0, 0);
                    s = __builtin_amdgcn_mfma_f32_16x16x32_f16(kf[1], qf[qn][1], s, 0, 0, 0);
                    S[jm][qn] = s;
                }
            }

            if (jt == qt) {
                #pragma unroll
                for (int jm = 0; jm < 8; jm++)
                    #pragma unroll
                    for (int qn = 0; qn < 2; qn++)
                        #pragma unroll
                        for (int r = 0; r < 4; r++) {
                            int jl = jm * 16 + quad * 4 + r;
                            int ql = w * 32 + qn * 16 + l16;
                            if (jl > ql) S[jm][qn][r] = -1e30f;
                        }
            }

            float alpha[2];
            #pragma unroll
            for (int qn = 0; qn < 2; qn++) {
                float tmax = -INFINITY;
                #pragma unroll
                for (int jm = 0; jm < 8; jm++)
                    #pragma unroll
                    for (int r = 0; r < 4; r++)
                        tmax = fmaxf(tmax, S[jm][qn][r]);
                tmax = fmaxf(tmax, __shfl_xor(tmax, 16));
                tmax = fmaxf(tmax, __shfl_xor(tmax, 32));
                float mnew = fmaxf(m_r[qn], tmax);
                alpha[qn] = __expf(m_r[qn] - mnew);
                m_r[qn] = mnew;
                float rsum = 0.0f;
                #pragma unroll
                for (int jm = 0; jm < 8; jm++)
                    #pragma unroll
                    for (int r = 0; r < 4; r++) {
                        float p = __expf(S[jm][qn][r] - mnew);
                        S[jm][qn][r] = p;
                        rsum += p;
                    }
                rsum += __shfl_xor(rsum, 16);
                rsum += __shfl_xor(rsum, 32);
                l_r[qn] = l_r[qn] * alpha[qn] + rsum;
            }

            #pragma unroll
            for (int jm = 0; jm < 8; jm++)
                #pragma unroll
                for (int qn = 0; qn < 2; qn++) {
                    f16x4 pk;
                    pk.x = (f16)S[jm][qn][0];
                    pk.y = (f16)S[jm][qn][1];
                    pk.z = (f16)S[jm][qn][2];
                    pk.w = (f16)S[jm][qn][3];
                    *(f16x4*)(Ps + (size_t)(qn * 16 + l16) * 136 + jm * 16 + quad * 4) = pk;
                }

            float aPV[2][4];
            #pragma unroll
            for (int m = 0; m < 2; m++)
                #pragma unroll
                for (int r = 0; r < 4; r++)
                    aPV[m][r] = __shfl(alpha[m], quad * 20 + r);
            #pragma unroll
            for (int m = 0; m < 2; m++)
                #pragma unroll
                for (int n = 0; n < 4; n++)
                    #pragma unroll
                    for (int r = 0; r < 4; r++)
                        Oacc[m][n][r] *= aPV[m][r];

            #pragma unroll
            for (int kblk = 0; kblk < 4; kblk++) {
                f16x8 pf[2];
                #pragma unroll
                for (int m = 0; m < 2; m++)
                    pf[m] = *(const f16x8*)(Ps + (size_t)(m * 16 + l16) * 136 +
                                            kblk * 32 + quad * 8);
                f16x8 vf[4];
                #pragma unroll
                for (int n = 0; n < 4; n++) {
                    int d = n * 16 + l16;
                    int g = (kblk * 4 + quad);
                    int gs = (g & 8) | ((g ^ d) & 7);
                    vf[n] = *(const f16x8*)(Vs + (size_t)(d * 16 + gs) * 8);
                }
                #pragma unroll
                for (int m = 0; m < 2; m++)
                    #pragma unroll
                    for (int n = 0; n < 4; n++)
                        Oacc[m][n] = __builtin_amdgcn_mfma_f32_16x16x32_f16(
                            pf[m], vf[n], Oacc[m][n], 0, 0, 0);
            }
        }

        #pragma unroll
        for (int m = 0; m < 2; m++) {
            float lPV[4];
            #pragma unroll
            for (int r = 0; r < 4; r++)
                lPV[r] = 1.0f / __shfl(l_r[m], quad * 20 + r);
            #pragma unroll
            for (int n = 0; n < 4; n++) {
                #pragma unroll
                for (int r = 0; r < 4; r++) {
                    int q = q0 + w * 32 + m * 16 + quad * 4 + r;
                    y[(size_t)(b * T_SEQ + q) * N_EMB + h * 64 + n * 16 + l16] =
                        (f16)(Oacc[m][n][r] * lPV[r]);
                }
            }
        }
    }
}

// ---------------------------------------------------------------- launch
extern "C" void kernel_launch(void* const* d_in, const int* in_sizes, int n_in,
                              void* d_out, int out_size, void* d_ws, size_t ws_size,
                              hipStream_t stream) {
    const float* x      = (const float*)d_in[0];
    const float* ln1_g  = (const float*)d_in[1];
    const float* ln1_b  = (const float*)d_in[2];
    const float* w_attn = (const float*)d_in[3];
    const float* b_attn = (const float*)d_in[4];
    const float* w_proj = (const float*)d_in[5];
    const float* b_proj = (const float*)d_in[6];
    const float* ln2_g  = (const float*)d_in[7];
    const float* ln2_b  = (const float*)d_in[8];
    const float* w_fc   = (const float*)d_in[9];
    const float* b_fc   = (const float*)d_in[10];
    const float* w_fc2  = (const float*)d_in[11];
    const float* b_fc2  = (const float*)d_in[12];
    float* out = (float*)d_out;

    const size_t MB = 1024 * 1024;
    char* ws = (char*)d_ws;
    f16*   lnbuf = (f16*)ws;                        // 16 MB
    f16*   qkbuf = (f16*)(ws + 16 * MB);            // 32 MB: [M][2048] Q|K
    f16*   vTbuf = (f16*)(ws + 48 * MB);            // 16 MB: [b][h][d][t]
    f16*   ybuf  = (f16*)(ws + 64 * MB);            // 16 MB
    f16*   h     = (f16*)(ws + 80 * MB);            // 64 MB
    f16*   wT    = (f16*)(ws + 144 * MB);           // 26 MB
    f16* wT_attn = wT;
    f16* wT_proj = wT_attn + (size_t)3072 * 1024;
    f16* wT_fc   = wT_proj + (size_t)1024 * 1024;
    f16* wT_fc2  = wT_fc   + (size_t)1024 * 4096;

    wconv_kernel<<<dim3(3072 / 32, 1024 / 32), 256, 0, stream>>>(w_attn, wT_attn, 1024, 3072);
    wconv_kernel<<<dim3(1024 / 32, 1024 / 32), 256, 0, stream>>>(w_proj, wT_proj, 1024, 1024);
    wconv_kernel<<<dim3(4096 / 32, 1024 / 32), 256, 0, stream>>>(w_fc,   wT_fc,   1024, 4096);
    wconv_kernel<<<dim3(1024 / 32, 4096 / 32), 256, 0, stream>>>(w_fc2,  wT_fc2,  4096, 1024);

    ln_kernel<<<M_ROWS, 256, 0, stream>>>(x, ln1_g, ln1_b, lnbuf);
    gemm_f16<3><<<dim3(3072 / 128, M_ROWS / 256), 256, 0, stream>>>(
        lnbuf, wT_attn, b_attn, nullptr, nullptr, qkbuf, vTbuf, 1024, 3072);
    flash_kernel<<<dim3(8, 64), 256, 0, stream>>>(qkbuf, vTbuf, ybuf);
    gemm_f16<1><<<dim3(1024 / 128, M_ROWS / 256), 256, 0, stream>>>(
        ybuf, wT_proj, b_proj, x, out, nullptr, nullptr, 1024, 1024);
    ln_kernel<<<M_ROWS, 256, 0, stream>>>(out, ln2_g, ln2_b, lnbuf);
    gemm_f16<2><<<dim3(4096 / 128, M_ROWS / 256), 256, 0, stream>>>(
        lnbuf, wT_fc, b_fc, nullptr, nullptr, h, nullptr, 1024, 4096);
    gemm_f16<1><<<dim3(1024 / 128, M_ROWS / 256), 256, 0, stream>>>(
        h, wT_fc2, b_fc2, out, out, nullptr, nullptr, 4096, 1024);
}

// Round 5
// 527.544 us; speedup vs baseline: 1.1216x; 1.1216x over previous
//
#include <hip/hip_runtime.h>
#include <math.h>

// Round 9 (resubmit — round 4 bench was a GPU-acquisition timeout, no data):
// per-GEMM tile selection + corrected 2-way LDS swizzle.
// BM=256 (wave tile 128x64, 375 B/MFMA) for qkv & fc (grids 768/1024 blocks,
// 2 blocks/CU). BM=128 (wave tile 64x64) for proj & fc2 (N=1024: grid must be
// 512 blocks for 2 blocks/CU — round-8 regression was 256-block grids).
// Swizzle: granule ^= (row>>1)&3 (staging source pre-swizzle + read-side),
// giving 2-way bank aliasing (free) vs round-8's 4-way / round-7's 8-way.
// 3 LDS buffers, dist-2 DMA prefetch, counted vmcnt (never 0 mid-loop),
// 1 barrier/iter, setprio around MFMA. Flash (paired q-tiles)/LN/wconv as-is.
//
// ws: [0,16M) lnbuf | [16,48M) qk | [48,64M) vT | [64,80M) ybuf
//     [80,144M) h | [144,170M) wT

#define M_ROWS 8192
#define T_SEQ 2048
#define N_EMB 1024
#define N_HEADS 16
#define HEAD_D 64

typedef _Float16 f16;
typedef __attribute__((ext_vector_type(8))) _Float16 f16x8;
typedef __attribute__((ext_vector_type(4))) _Float16 f16x4;
typedef __attribute__((ext_vector_type(4))) float f32x4;

__device__ __forceinline__ void async16(void* lds, const void* g) {
    __builtin_amdgcn_global_load_lds(
        (const __attribute__((address_space(1))) unsigned int*)g,
        (__attribute__((address_space(3))) unsigned int*)lds, 16, 0, 0);
}

__device__ __forceinline__ float gelu_tanh(float v) {
    float u = 0.7978845608028654f * (v + 0.044715f * v * v * v);
    float e = __expf(2.0f * u);
    float t = 1.0f - 2.0f / (e + 1.0f);
    return 0.5f * v * (1.0f + t);
}

// ---------------------------------------------------------------- weight convert
__launch_bounds__(256)
__global__ void wconv_kernel(const float* __restrict__ W, f16* __restrict__ WT,
                             int K, int N) {
    __shared__ float t[32][33];
    int tx = threadIdx.x & 31, ty = threadIdx.x >> 5;
    int n0 = blockIdx.x * 32, k0 = blockIdx.y * 32;
    #pragma unroll
    for (int r = 0; r < 4; r++)
        t[ty * 4 + r][tx] = W[(size_t)(k0 + ty * 4 + r) * N + n0 + tx];
    __syncthreads();
    #pragma unroll
    for (int r = 0; r < 4; r++)
        WT[(size_t)(n0 + ty * 4 + r) * K + k0 + tx] = (f16)t[tx][ty * 4 + r];
}

// ---------------------------------------------------------------- LayerNorm -> f16
__launch_bounds__(256)
__global__ void ln_kernel(const float* __restrict__ x, const float* __restrict__ g,
                          const float* __restrict__ b, f16* __restrict__ y) {
    int row = blockIdx.x;
    int tid = threadIdx.x;
    const float* xr = x + (size_t)row * N_EMB;
    float4 v = *(const float4*)(xr + tid * 4);
    float s  = v.x + v.y + v.z + v.w;
    float sq = v.x * v.x + v.y * v.y + v.z * v.z + v.w * v.w;
    #pragma unroll
    for (int off = 32; off > 0; off >>= 1) {
        s  += __shfl_down(s, off);
        sq += __shfl_down(sq, off);
    }
    __shared__ float ws_[4], wq_[4];
    __shared__ float mean_s, rstd_s;
    int lane = tid & 63, wid = tid >> 6;
    if (lane == 0) { ws_[wid] = s; wq_[wid] = sq; }
    __syncthreads();
    if (tid == 0) {
        float st = ws_[0] + ws_[1] + ws_[2] + ws_[3];
        float qt = wq_[0] + wq_[1] + wq_[2] + wq_[3];
        float mu = st * (1.0f / N_EMB);
        float var = qt * (1.0f / N_EMB) - mu * mu;
        mean_s = mu;
        rstd_s = rsqrtf(var + 1e-5f);
    }
    __syncthreads();
    float mu = mean_s, r = rstd_s;
    float4 gv = *(const float4*)(g + tid * 4);
    float4 bv = *(const float4*)(b + tid * 4);
    f16x4 o;
    o.x = (f16)((v.x - mu) * r * gv.x + bv.x);
    o.y = (f16)((v.y - mu) * r * gv.y + bv.y);
    o.z = (f16)((v.z - mu) * r * gv.z + bv.z);
    o.w = (f16)((v.w - mu) * r * gv.w + bv.w);
    *(f16x4*)(y + (size_t)row * N_EMB + tid * 4) = o;
}

// ---------------------------------------------------------------- GEMM f16 MFMA
// Block tile BMx128, BK=32, 4 waves (2x2). BM=256: wave tile 128x64,
// acc[8][4]. BM=128: wave tile 64x64, acc[4][4].
// LDS granule swizzle: phys granule = logical ^ ((row>>1)&3) — staged via
// pre-swizzled GLOBAL source (LDS dest linear, gload_lds rule), read with the
// same involution -> 2-way bank aliasing (free).
// 3 buffers, dist-2 prefetch, vmcnt(L) steady state, 1 barrier/iter.
// EPI: 0 f32 | 1 f32 + f32 residual | 2 gelu->f16 | 3 qkv split
template <int EPI, int BM>
__launch_bounds__(256, 2)
__global__ void gemm_f16(const f16* __restrict__ A, const f16* __restrict__ Bt,
                         const float* __restrict__ bias, const float* __restrict__ res,
                         float* __restrict__ Cf, f16* __restrict__ Ch,
                         f16* __restrict__ vT, int K, int N) {
    constexpr int AR = BM / 64;        // A staging rounds (4KB each)
    constexpr int WM = BM / 2;         // wave tile m
    constexpr int MI = WM / 16;        // m fragments per wave
    constexpr int ABUF = BM * 64;      // bytes per A buffer
    constexpr int BBUF = 8192;         // bytes per B buffer
    __shared__ f16 As[3][BM * 32];
    __shared__ f16 Bs[3][128 * 32];
    int tid = threadIdx.x;
    int lane = tid & 63, wave = tid >> 6;
    int wr = wave >> 1, wc = wave & 1;
    int quad = lane >> 4, l16 = lane & 15;

    // bijective XCD swizzle (all gemm grids divisible by 8)
    int nx = gridDim.x;
    int nwg = nx * gridDim.y;
    int orig = blockIdx.y * nx + blockIdx.x;
    int cpx = nwg >> 3;
    int swz = (orig & 7) * cpx + (orig >> 3);
    int m0 = (swz / nx) * BM, n0 = (swz % nx) * 128;

    // staging: one round = 256 thr x 16B = 4KB = 64 rows (row stride 64B).
    // phys granule slot tid&3 of row srow holds logical granule (tid&3)^s(row),
    // s(row) = (row>>1)&3 (invariant under +64-row rounds).
    int srow = tid >> 2;
    int sg = (tid & 3) ^ ((srow >> 1) & 3);
    const f16* pA = A  + (size_t)(m0 + srow) * K + sg * 8;
    const f16* pB = Bt + (size_t)(n0 + srow) * K + sg * 8;
    char* dA = (char*)As + (size_t)tid * 16;
    char* dB = (char*)Bs + (size_t)tid * 16;

    int nt = K >> 5;

    // prologue: tiles 0 and 1 (2L loads in flight)
    #pragma unroll
    for (int tt = 0; tt < 2; tt++) {
        #pragma unroll
        for (int r = 0; r < AR; r++)
            async16(dA + tt * ABUF + r * 4096, pA + (size_t)(r * 64) * K + tt * 32);
        #pragma unroll
        for (int r = 0; r < 2; r++)
            async16(dB + tt * BBUF + r * 4096, pB + (size_t)(r * 64) * K + tt * 32);
    }

    f32x4 acc[MI][4] = {};
    int cswz = (quad ^ ((l16 >> 1) & 3)) * 8;
    int bufr = 0;
    for (int t = 0; t < nt; t++) {
        if (t + 1 < nt) {
            if constexpr (BM == 256) asm volatile("s_waitcnt vmcnt(6)" ::: "memory");
            else                     asm volatile("s_waitcnt vmcnt(4)" ::: "memory");
        } else {
            asm volatile("s_waitcnt vmcnt(0)" ::: "memory");
        }
        __builtin_amdgcn_s_barrier();   // tile t visible; buf (t+2)%3 reads retired

        const f16* as = As[bufr];
        const f16* bs = Bs[bufr];
        int bn = bufr + 2 >= 3 ? bufr - 1 : bufr + 2;   // (t+2)%3
        if (t + 2 < nt) {
            size_t koff = (size_t)(t + 2) * 32;
            #pragma unroll
            for (int r = 0; r < AR; r++)
                async16(dA + bn * ABUF + r * 4096, pA + (size_t)(r * 64) * K + koff);
            #pragma unroll
            for (int r = 0; r < 2; r++)
                async16(dB + bn * BBUF + r * 4096, pB + (size_t)(r * 64) * K + koff);
        }

        f16x8 bf[4];
        #pragma unroll
        for (int j = 0; j < 4; j++)
            bf[j] = *(const f16x8*)&bs[(wc * 64 + j * 16 + l16) * 32 + cswz];
        f16x8 af[MI];
        #pragma unroll
        for (int i = 0; i < MI; i++)
            af[i] = *(const f16x8*)&as[(wr * WM + i * 16 + l16) * 32 + cswz];
        __builtin_amdgcn_s_setprio(1);
        #pragma unroll
        for (int i = 0; i < MI; i++)
            #pragma unroll
            for (int j = 0; j < 4; j++)
                acc[i][j] = __builtin_amdgcn_mfma_f32_16x16x32_f16(
                    af[i], bf[j], acc[i][j], 0, 0, 0);
        __builtin_amdgcn_s_setprio(0);

        bufr = bufr + 1 >= 3 ? 0 : bufr + 1;
    }

    // epilogue: C/D layout col=lane&15, row=quad*4+r
    #pragma unroll
    for (int i = 0; i < MI; i++) {
        int row0 = m0 + wr * WM + i * 16 + quad * 4;
        #pragma unroll
        for (int j = 0; j < 4; j++) {
            int col = n0 + wc * 64 + j * 16 + l16;
            float bb = bias[col];
            if (EPI == 3) {
                if (n0 < 2048) {
                    #pragma unroll
                    for (int r = 0; r < 4; r++)
                        Ch[(size_t)(row0 + r) * 2048 + col] = (f16)(acc[i][j][r] + bb);
                } else {
                    int hh = (col - 2048) >> 6, dd = col & 63;
                    int bb_ = row0 >> 11, t0 = row0 & 2047;
                    f16x4 pk;
                    pk.x = (f16)(acc[i][j][0] + bb);
                    pk.y = (f16)(acc[i][j][1] + bb);
                    pk.z = (f16)(acc[i][j][2] + bb);
                    pk.w = (f16)(acc[i][j][3] + bb);
                    *(f16x4*)(vT + ((size_t)(bb_ * 16 + hh) * 64 + dd) * 2048 + t0) = pk;
                }
            } else {
                #pragma unroll
                for (int r = 0; r < 4; r++) {
                    size_t idx = (size_t)(row0 + r) * N + col;
                    float v = acc[i][j][r] + bb;
                    if (EPI == 1) v += res[idx];
                    if (EPI == 2) Ch[idx] = (f16)gelu_tanh(v);
                    else          Cf[idx] = v;
                }
            }
        }
    }
}

// ---------------------------------------------------------------- MFMA flash
// 256 thr = 4 waves; 128 q-rows per tile (wave w owns 32), 128-wide j-tiles.
// S^T = K.Q^T (C-layout: 4 consecutive j per lane). Q pre-scaled by 1/8.
// CAUSAL BALANCING: each block processes TWO q-tiles, qt = 15-x then qt = x,
// so every block does exactly 17 j-tile iterations. Grid = (8, 64) = 512
// blocks = 2 blocks/CU (LDS limit) -> all blocks co-resident, uniform work.
__launch_bounds__(256, 2)
__global__ void flash_kernel(const f16* __restrict__ qk, const f16* __restrict__ vT,
                             f16* __restrict__ y) {
    __shared__ __align__(16) char smem[67584];
    f16* Ks = (f16*)smem;                      // [128 j][8 g of 8 d], g^=(j&7)
    f16* Vs = (f16*)(smem + 16384);            // [64 d][16 g of 8 j], g^=(d&7)
    int tid = threadIdx.x;
    int lane = tid & 63, w = tid >> 6;
    int quad = lane >> 4, l16 = lane & 15;
    f16* Ps = (f16*)(smem + 32768 + w * 8704); // per-wave [32 q][136 j]

    int bh = blockIdx.y;
    int b = bh >> 4, h = bh & 15;

    for (int half = 0; half < 2; half++) {
        int qt = half ? (int)blockIdx.x : 15 - (int)blockIdx.x;
        int q0 = qt * 128;

        // Q B-frags, pre-scaled by 1/sqrt(D)=0.125 (exact in f16)
        f16x8 qf[2][2];
        #pragma unroll
        for (int qn = 0; qn < 2; qn++) {
            int q = q0 + w * 32 + qn * 16 + l16;
            #pragma unroll
            for (int dblk = 0; dblk < 2; dblk++) {
                f16x8 t = *(const f16x8*)(qk + (size_t)(b * T_SEQ + q) * 2048 +
                                          h * 64 + dblk * 32 + quad * 8);
                #pragma unroll
                for (int e = 0; e < 8; e++) t[e] = t[e] * (f16)0.125f;
                qf[qn][dblk] = t;
            }
        }

        float m_r[2] = {-INFINITY, -INFINITY};
        float l_r[2] = {0.0f, 0.0f};
        f32x4 Oacc[2][4] = {};

        for (int jt = 0; jt <= qt; jt++) {
            int j0 = jt * 128;
            __syncthreads();   // prior iter's (or prior half's) LDS reads done
            #pragma unroll
            for (int i = 0; i < 4; i++) {
                int L = i * 256 + tid;
                int j = L >> 3, g1 = L & 7;
                int g = g1 ^ (j & 7);
                async16((char*)Ks + (size_t)L * 16,
                        qk + (size_t)(b * T_SEQ + j0 + j) * 2048 + 1024 + h * 64 + g * 8);
            }
            #pragma unroll
            for (int i = 0; i < 4; i++) {
                int L = i * 256 + tid;
                int d = L >> 4, g1 = L & 15;
                int g = (g1 & 8) | ((g1 ^ d) & 7);
                async16((char*)Vs + (size_t)L * 16,
                        vT + ((size_t)(bh) * 64 + d) * 2048 + j0 + g * 8);
            }
            __syncthreads();

            // S^T = K . Q^T (pre-scaled)
            f32x4 S[8][2];
            #pragma unroll
            for (int jm = 0; jm < 8; jm++) {
                f16x8 kf[2];
                #pragma unroll
                for (int dblk = 0; dblk < 2; dblk++) {
                    int j = jm * 16 + l16;
                    int g = (dblk * 4 + quad) ^ (j & 7);
                    kf[dblk] = *(const f16x8*)(Ks + (size_t)(j * 8 + g) * 8);
                }
                #pragma unroll
                for (int qn = 0; qn < 2; qn++) {
                    f32x4 s = {};
                    s = __builtin_amdgcn_mfma_f32_16x16x32_f16(kf[0], qf[qn][0], s, 0, 0, 0);
                    s = __builtin_amdgcn_mfma_f32_16x16x32_f16(kf[1], qf[qn][1], s, 0, 0, 0);
                    S[jm][qn] = s;
                }
            }

            if (jt == qt) {
                #pragma unroll
                for (int jm = 0; jm < 8; jm++)
                    #pragma unroll
                    for (int qn = 0; qn < 2; qn++)
                        #pragma unroll
                        for (int r = 0; r < 4; r++) {
                            int jl = jm * 16 + quad * 4 + r;
                            int ql = w * 32 + qn * 16 + l16;
                            if (jl > ql) S[jm][qn][r] = -1e30f;
                        }
            }

            float alpha[2];
            #pragma unroll
            for (int qn = 0; qn < 2; qn++) {
                float tmax = -INFINITY;
                #pragma unroll
                for (int jm = 0; jm < 8; jm++)
                    #pragma unroll
                    for (int r = 0; r < 4; r++)
                        tmax = fmaxf(tmax, S[jm][qn][r]);
                tmax = fmaxf(tmax, __shfl_xor(tmax, 16));
                tmax = fmaxf(tmax, __shfl_xor(tmax, 32));
                float mnew = fmaxf(m_r[qn], tmax);
                alpha[qn] = __expf(m_r[qn] - mnew);
                m_r[qn] = mnew;
                float rsum = 0.0f;
                #pragma unroll
                for (int jm = 0; jm < 8; jm++)
                    #pragma unroll
                    for (int r = 0; r < 4; r++) {
                        float p = __expf(S[jm][qn][r] - mnew);
                        S[jm][qn][r] = p;
                        rsum += p;
                    }
                rsum += __shfl_xor(rsum, 16);
                rsum += __shfl_xor(rsum, 32);
                l_r[qn] = l_r[qn] * alpha[qn] + rsum;
            }

            #pragma unroll
            for (int jm = 0; jm < 8; jm++)
                #pragma unroll
                for (int qn = 0; qn < 2; qn++) {
                    f16x4 pk;
                    pk.x = (f16)S[jm][qn][0];
                    pk.y = (f16)S[jm][qn][1];
                    pk.z = (f16)S[jm][qn][2];
                    pk.w = (f16)S[jm][qn][3];
                    *(f16x4*)(Ps + (size_t)(qn * 16 + l16) * 136 + jm * 16 + quad * 4) = pk;
                }

            float aPV[2][4];
            #pragma unroll
            for (int m = 0; m < 2; m++)
                #pragma unroll
                for (int r = 0; r < 4; r++)
                    aPV[m][r] = __shfl(alpha[m], quad * 20 + r);
            #pragma unroll
            for (int m = 0; m < 2; m++)
                #pragma unroll
                for (int n = 0; n < 4; n++)
                    #pragma unroll
                    for (int r = 0; r < 4; r++)
                        Oacc[m][n][r] *= aPV[m][r];

            #pragma unroll
            for (int kblk = 0; kblk < 4; kblk++) {
                f16x8 pf[2];
                #pragma unroll
                for (int m = 0; m < 2; m++)
                    pf[m] = *(const f16x8*)(Ps + (size_t)(m * 16 + l16) * 136 +
                                            kblk * 32 + quad * 8);
                f16x8 vf[4];
                #pragma unroll
                for (int n = 0; n < 4; n++) {
                    int d = n * 16 + l16;
                    int g = (kblk * 4 + quad);
                    int gs = (g & 8) | ((g ^ d) & 7);
                    vf[n] = *(const f16x8*)(Vs + (size_t)(d * 16 + gs) * 8);
                }
                #pragma unroll
                for (int m = 0; m < 2; m++)
                    #pragma unroll
                    for (int n = 0; n < 4; n++)
                        Oacc[m][n] = __builtin_amdgcn_mfma_f32_16x16x32_f16(
                            pf[m], vf[n], Oacc[m][n], 0, 0, 0);
            }
        }

        #pragma unroll
        for (int m = 0; m < 2; m++) {
            float lPV[4];
            #pragma unroll
            for (int r = 0; r < 4; r++)
                lPV[r] = 1.0f / __shfl(l_r[m], quad * 20 + r);
            #pragma unroll
            for (int n = 0; n < 4; n++) {
                #pragma unroll
                for (int r = 0; r < 4; r++) {
                    int q = q0 + w * 32 + m * 16 + quad * 4 + r;
                    y[(size_t)(b * T_SEQ + q) * N_EMB + h * 64 + n * 16 + l16] =
                        (f16)(Oacc[m][n][r] * lPV[r]);
                }
            }
        }
    }
}

// ---------------------------------------------------------------- launch
extern "C" void kernel_launch(void* const* d_in, const int* in_sizes, int n_in,
                              void* d_out, int out_size, void* d_ws, size_t ws_size,
                              hipStream_t stream) {
    const float* x      = (const float*)d_in[0];
    const float* ln1_g  = (const float*)d_in[1];
    const float* ln1_b  = (const float*)d_in[2];
    const float* w_attn = (const float*)d_in[3];
    const float* b_attn = (const float*)d_in[4];
    const float* w_proj = (const float*)d_in[5];
    const float* b_proj = (const float*)d_in[6];
    const float* ln2_g  = (const float*)d_in[7];
    const float* ln2_b  = (const float*)d_in[8];
    const float* w_fc   = (const float*)d_in[9];
    const float* b_fc   = (const float*)d_in[10];
    const float* w_fc2  = (const float*)d_in[11];
    const float* b_fc2  = (const float*)d_in[12];
    float* out = (float*)d_out;

    const size_t MB = 1024 * 1024;
    char* ws = (char*)d_ws;
    f16*   lnbuf = (f16*)ws;                        // 16 MB
    f16*   qkbuf = (f16*)(ws + 16 * MB);            // 32 MB: [M][2048] Q|K
    f16*   vTbuf = (f16*)(ws + 48 * MB);            // 16 MB: [b][h][d][t]
    f16*   ybuf  = (f16*)(ws + 64 * MB);            // 16 MB
    f16*   h     = (f16*)(ws + 80 * MB);            // 64 MB
    f16*   wT    = (f16*)(ws + 144 * MB);           // 26 MB
    f16* wT_attn = wT;
    f16* wT_proj = wT_attn + (size_t)3072 * 1024;
    f16* wT_fc   = wT_proj + (size_t)1024 * 1024;
    f16* wT_fc2  = wT_fc   + (size_t)1024 * 4096;

    wconv_kernel<<<dim3(3072 / 32, 1024 / 32), 256, 0, stream>>>(w_attn, wT_attn, 1024, 3072);
    wconv_kernel<<<dim3(1024 / 32, 1024 / 32), 256, 0, stream>>>(w_proj, wT_proj, 1024, 1024);
    wconv_kernel<<<dim3(4096 / 32, 1024 / 32), 256, 0, stream>>>(w_fc,   wT_fc,   1024, 4096);
    wconv_kernel<<<dim3(1024 / 32, 4096 / 32), 256, 0, stream>>>(w_fc2,  wT_fc2,  4096, 1024);

    ln_kernel<<<M_ROWS, 256, 0, stream>>>(x, ln1_g, ln1_b, lnbuf);
    gemm_f16<3, 256><<<dim3(3072 / 128, M_ROWS / 256), 256, 0, stream>>>(
        lnbuf, wT_attn, b_attn, nullptr, nullptr, qkbuf, vTbuf, 1024, 3072);
    flash_kernel<<<dim3(8, 64), 256, 0, stream>>>(qkbuf, vTbuf, ybuf);
    gemm_f16<1, 128><<<dim3(1024 / 128, M_ROWS / 128), 256, 0, stream>>>(
        ybuf, wT_proj, b_proj, x, out, nullptr, nullptr, 1024, 1024);
    ln_kernel<<<M_ROWS, 256, 0, stream>>>(out, ln2_g, ln2_b, lnbuf);
    gemm_f16<2, 256><<<dim3(4096 / 128, M_ROWS / 256), 256, 0, stream>>>(
        lnbuf, wT_fc, b_fc, nullptr, nullptr, h, nullptr, 1024, 4096);
    gemm_f16<1, 128><<<dim3(1024 / 128, M_ROWS / 128), 256, 0, stream>>>(
        h, wT_fc2, b_fc2, out, out, nullptr, nullptr, 4096, 1024);
}